// Round 13
// baseline (424.059 us; speedup 1.0000x reference)
//
#include <hip/hip_runtime.h>
#include <hip/hip_bf16.h>
#include <math.h>
#include <cstdint>

typedef unsigned long long u64;
typedef unsigned int u32;
typedef _Float16 half8 __attribute__((ext_vector_type(8)));
typedef _Float16 half4 __attribute__((ext_vector_type(4)));
typedef _Float16 half2t __attribute__((ext_vector_type(2)));
typedef float floatx4 __attribute__((ext_vector_type(4)));

// ---------------------------------------------------------------------------
// Sizes
// ---------------------------------------------------------------------------
#define NANCH 36864        // 4096*9
#define SEG 65536          // per-image key segment stride (layout only)
#define N_PRE 6000
#define N_POST 300
#define NW 96              // mask words per row (6144 bits)
#define NPADC 6144         // padded candidate count
#define CAP 8192           // compaction buffer capacity per image

// output float offsets
#define O0 0               // rpn_locs  2*36864*4 = 294912
#define O1 294912          // rpn_scores 2*36864*2 = 147456
#define O2 442368          // rois 2*300*4 = 2400
#define O3 444768          // roi_indices 600
#define O4 445368          // anchor 147456
#define O5 592824          // vmask 600

// workspace float offsets
#define WS_XHI   0                        // xhi f16 [2][4096][512] (2,097,152 f)
#define WS_XLO   2097152
#define WS_WHI   4194304                  // whi f16 [9][512][512] (1,179,648 f)
#define WS_WLO   5373952
#define WS_WSLT  6553600                  // 32768
#define WS_WSLB  6586368                  // 64
#define WS_H     6586432                  // hbuf f32 [2][4096][512] = 4,194,304 f
#define WS_GUARD 10780736                 // 64 floats of zeros (OOB target)
// overlays into dead XHI region (used only after conv completes):
#define WS_FG    0                        // 73728
#define WS_ROI   73728                    // 294912 (16B aligned)
#define WS_KEYS  368640                   // 131072 u64 = 262144 f
#define WS_SBOX  630784                   // 2*6144 float4 = 49152 f
#define WS_ALIVE 679936                   // 2*96 u64 = 384 f
#define WS_CBUF  680320                   // 2*8192 u64 = 32768 f (ends at WS_HIST)
#define WS_HIST  713088                   // 2*65536 u32 = 131072 f
#define WS_RANK  844160                   // 2*8192 u32 = 16384 f
#define WS_CNT   860544                   // [0,1]=cnt, [2,3]=T
// overlay into dead WHI+WLO region (after conv): FULL suppression matrix
#define WS_MASK  4194304                  // 2*6144*96 u64 = 9,437,184 B (exact fit)

#define HSCALE 9.5367431640625e-07f       // 2^-20

// ---------------------------------------------------------------------------
__device__ __forceinline__ void gl_lds16(const void* g, void* l) {
  __builtin_amdgcn_global_load_lds(
      (const __attribute__((address_space(1))) u32*)g,
      (__attribute__((address_space(3))) u32*)l, 16, 0, 0);
}

__device__ __forceinline__ u64 bcast64(u64 v, int src) {
  u32 lo = (u32)__shfl((int)(v & 0xFFFFFFFFull), src);
  u32 hi = (u32)__shfl((int)(v >> 32), src);
  return ((u64)hi << 32) | lo;
}

// padded u32 index for scans (stride-2^k accesses)
__device__ __forceinline__ int SCX(int t) { return t + (t >> 5); }

// ---------------------------------------------------------------------------
// 0. fused prep: zero hbuf+guard | xcvt | wcvt | head-weight pack.
// Grid: [0,4097) zero | [4097,5121) xcvt | [5121,5377) wcvt | [5377,5506) small.
// ---------------------------------------------------------------------------
__global__ __launch_bounds__(256) void prep_all(
    const float* __restrict__ x, const float* __restrict__ w,
    const float* __restrict__ lw, const float* __restrict__ sw,
    const float* __restrict__ lb, const float* __restrict__ sb,
    float4* __restrict__ h, float4* __restrict__ guard,
    _Float16* __restrict__ xhi, _Float16* __restrict__ xlo,
    _Float16* __restrict__ whi, _Float16* __restrict__ wlo,
    float* __restrict__ wslt, float* __restrict__ wslb) {
  const int b = blockIdx.x, tid = threadIdx.x;
  if (b < 4097) {
    int idx = b * 256 + tid;
    if (idx < 1048576) h[idx] = make_float4(0.f, 0.f, 0.f, 0.f);
    else if (idx < 1048576 + 16) guard[idx - 1048576] = make_float4(0.f, 0.f, 0.f, 0.f);
    return;
  }
  if (b < 5121) {  // xcvt: [n][c][pix] f32 -> [n][pix][c] f16 hi/lo x1024
    __shared__ float s[64 * 65];
    int l = b - 4097;
    int pt = l & 63, cg = (l >> 6) & 7, n = l >> 9;
    const int c0 = cg << 6, p0 = pt << 6;
#pragma unroll
    for (int kk = 0; kk < 4; ++kk) {   // 1024 float4 loads: 64 ci x 16 quads
      int e = tid + (kk << 8);
      int ci = e >> 4, pi = (e & 15) << 2;
      float4 v = *(const float4*)&x[(((size_t)(n * 512 + c0 + ci)) << 12) + p0 + pi];
      s[ci * 65 + pi + 0] = v.x;
      s[ci * 65 + pi + 1] = v.y;
      s[ci * 65 + pi + 2] = v.z;
      s[ci * 65 + pi + 3] = v.w;
    }
    __syncthreads();
#pragma unroll
    for (int kk = 0; kk < 4; ++kk) {   // 1024 quads: 64 pi x 16 ci-quads
      int e = tid + (kk << 8);
      int pi = e >> 4, ci = (e & 15) << 2;
      half4 hv, lv;
#pragma unroll
      for (int j = 0; j < 4; ++j) {
        float sv = s[(ci + j) * 65 + pi] * 1024.f;
        _Float16 hi = (_Float16)sv;
        hv[j] = hi;
        lv[j] = (_Float16)(sv - (float)hi);
      }
      size_t off = (((size_t)(n << 12) + p0 + pi) << 9) + c0 + ci;
      *(half4*)(xhi + off) = hv;
      *(half4*)(xlo + off) = lv;
    }
    return;
  }
  if (b < 5377) {  // wcvt: [o][c][3][3] -> [t][o][c] f16 hi/lo x1024
    __shared__ float sw_[16 * 584];    // 16 o-rows x 576 (+8 pad) = 37.4 KB
    int l = b - 5121;                  // 0..255
    int ot = l >> 3, ct = l & 7;       // 32 o-tiles(16) x 8 c-tiles(64)
    const int o0 = ot << 4, c0 = ct << 6;
    for (int e = tid; e < 9216; e += 256) {   // coalesced slab read
      int r = e / 576, j = e - r * 576;
      sw_[r * 584 + j] = w[(size_t)(o0 + r) * 4608 + (size_t)c0 * 9 + j];
    }
    __syncthreads();
    for (int e = tid; e < 4608; e += 256) {   // pairs (t, r, ci-even)
      int t = e / 512, rem = e - t * 512;
      int r = rem >> 5, cp = rem & 31, ci = cp << 1;
      float v0 = sw_[r * 584 + ci * 9 + t] * 1024.f;
      float v1 = sw_[r * 584 + (ci + 1) * 9 + t] * 1024.f;
      _Float16 h0 = (_Float16)v0, h1 = (_Float16)v1;
      half2t hh = {h0, h1};
      half2t ll = {(_Float16)(v0 - (float)h0), (_Float16)(v1 - (float)h1)};
      size_t off = ((size_t)((t << 9) + o0 + r) << 9) + c0 + ci;
      *(half2t*)(whi + off) = hh;
      *(half2t*)(wlo + off) = ll;
    }
    return;
  }
  {  // prep_small
    int e = (b - 5377) * 256 + tid;
    if (e < 32768) {
      int c = e >> 6, o = e & 63;
      float v = 0.f;
      if (o < 36) v = lw[o * 512 + c];
      else if (o < 54) v = sw[(o - 36) * 512 + c];
      wslt[e] = v;
    } else if (e < 32832) {
      int o = e - 32768;
      float v = 0.f;
      if (o < 36) v = lb[o];
      else if (o < 54) v = sb[o - 36];
      wslb[o] = v;
    }
  }
}

// ---------------------------------------------------------------------------
// 1. MFMA implicit-GEMM 3x3 conv (fp16x2 split: hh + hl + lh, fp32 acc).
// R0 structure, parked: 121us = ~960 TF effective on the 3-pass GEMM —
// at the plain-HIP 2-barrier-structure ceiling (m97/m103). Perturbations
// all regressed: R1 pipelined dbuf 129 | R2 pass-split 217 | R3 B-in-regs
// 169. Do not touch.
// ---------------------------------------------------------------------------
__global__ __launch_bounds__(256) void conv_mfma(
    const _Float16* __restrict__ xhi, const _Float16* __restrict__ xlo,
    const _Float16* __restrict__ whi, const _Float16* __restrict__ wlo,
    const float* __restrict__ guard, float* __restrict__ hout) {
  __shared__ _Float16 aHi[4 * 68 * 32];
  __shared__ _Float16 aLo[4 * 68 * 32];
  __shared__ _Float16 bHi[128 * 32];
  __shared__ _Float16 bLo[128 * 32];
  const int tid = threadIdx.x;
  const int lane = tid & 63, w = tid >> 6;
  const int ptile = blockIdx.x;
  const int og = blockIdx.y;
  const int kq = blockIdx.z;
  const int n = ptile >> 5;
  const int y0 = (ptile & 31) << 1;
  const int o0 = og << 7;
  const int l15 = lane & 15, l16 = lane >> 4;
  const int ry = w >> 1;
  const int wo = (w & 1) << 6;

  floatx4 acc[4][4];
#pragma unroll
  for (int a = 0; a < 4; ++a)
#pragma unroll
    for (int b = 0; b < 4; ++b) acc[a][b] = (floatx4)0.f;

  for (int s = 0; s < 8; ++s) {
    const int c0 = (kq << 8) + (s << 5);
    __syncthreads();
    for (int i = w; i < 17; i += 4) {
      int chunk = (i << 6) + lane;
      int p = chunk >> 2, q = chunk & 3;
      int r = p / 68, xs = p - r * 68;
      int y = y0 - 1 + r, xg = xs - 1;
      bool ok = ((unsigned)y < 64u) && ((unsigned)xg < 64u);
      size_t off = (((size_t)(n << 12) + (y << 6) + xg) << 9) + c0 + (q << 3);
      const void* gh = ok ? (const void*)(xhi + off) : (const void*)guard;
      const void* gl = ok ? (const void*)(xlo + off) : (const void*)guard;
      gl_lds16(gh, (char*)aHi + (i << 10));
      gl_lds16(gl, (char*)aLo + (i << 10));
    }
    for (int tt = 0; tt < 9; ++tt) {
      if (tt > 0) __syncthreads();
      for (int i = w; i < 8; i += 4) {
        int chunk = (i << 6) + lane;
        int row = chunk >> 2, q = chunk & 3;
        size_t off = ((size_t)((tt << 9) + o0 + row) << 9) + c0 + (q << 3);
        gl_lds16((const void*)(whi + off), (char*)bHi + (i << 10));
        gl_lds16((const void*)(wlo + off), (char*)bLo + (i << 10));
      }
      __syncthreads();

      const int dy = tt / 3, dx = tt - 3 * dy;
      half8 ah[4], al[4], bh[4], bl[4];
#pragma unroll
      for (int im = 0; im < 4; ++im) {
        int xp = (im << 4) + l15;
        int p = (ry + dy) * 68 + xp + dx;
        ah[im] = *(const half8*)&aHi[(p << 5) + (l16 << 3)];
        al[im] = *(const half8*)&aLo[(p << 5) + (l16 << 3)];
      }
#pragma unroll
      for (int in = 0; in < 4; ++in) {
        int orow = wo + (in << 4) + l15;
        bh[in] = *(const half8*)&bHi[(orow << 5) + (l16 << 3)];
        bl[in] = *(const half8*)&bLo[(orow << 5) + (l16 << 3)];
      }
#pragma unroll
      for (int im = 0; im < 4; ++im)
#pragma unroll
        for (int in = 0; in < 4; ++in) {
          acc[im][in] = __builtin_amdgcn_mfma_f32_16x16x32_f16(
              ah[im], bh[in], acc[im][in], 0, 0, 0);
          acc[im][in] = __builtin_amdgcn_mfma_f32_16x16x32_f16(
              ah[im], bl[in], acc[im][in], 0, 0, 0);
          acc[im][in] = __builtin_amdgcn_mfma_f32_16x16x32_f16(
              al[im], bh[in], acc[im][in], 0, 0, 0);
        }
    }
  }

#pragma unroll
  for (int im = 0; im < 4; ++im)
#pragma unroll
    for (int in = 0; in < 4; ++in) {
      int o = o0 + wo + (in << 4) + l15;
#pragma unroll
      for (int reg = 0; reg < 4; ++reg) {
        int m_local = (ry << 6) + (im << 4) + (l16 << 2) + reg;
        size_t off = (((size_t)(n << 12) + (y0 << 6) + m_local) << 9) + o;
        atomicAdd(&hout[off], acc[im][in][reg]);
      }
    }
}

// ---------------------------------------------------------------------------
// 2. 1x1 heads + softmax. grid (64 y, 2 n, 4 xq), block 256.
// ---------------------------------------------------------------------------
__global__ __launch_bounds__(256) void head_kernel(
    const float* __restrict__ hbuf, const float* __restrict__ cb,
    const float* __restrict__ wslt, const float* __restrict__ wslb,
    float* __restrict__ out, float* __restrict__ fgbuf,
    uint4* __restrict__ hist4) {
  const int y = blockIdx.x, n = blockIdx.y, xq = blockIdx.z;
  __shared__ float sH[16 * 17];
  __shared__ float sWt[1024];
  __shared__ float sOut[64 * 17];
  const int tid = threadIdx.x;
  const int x4 = tid & 15, og = tid >> 4;   // 16 x-positions, 16 out-groups
  const int x0 = xq << 4;                    // x-quarter base

  // init for the selection path (xq==0 blocks: 128 x 256 = 32768 lanes)
  if (xq == 0) {
    int gid = ((n << 6) + y) * 256 + tid;          // 0..32767
    hist4[gid] = make_uint4(0u, 0u, 0u, 0u);       // 512 KB = full hist
  }

  float acc[4];
#pragma unroll
  for (int j = 0; j < 4; ++j) acc[j] = 0.f;

  const float* hb = hbuf + (((size_t)(n << 12) + (y << 6) + x0) << 9);

  for (int c0 = 0; c0 < 512; c0 += 16) {
    __syncthreads();
    {  // stage sH: 16 ch x 16 x = 256 elems (1/thread)
      int cc = tid & 15, xx = tid >> 4;
      float raw = hb[((size_t)xx << 9) + c0 + cc];
      sH[cc * 17 + xx] = fmaxf(raw * HSCALE + cb[c0 + cc], 0.f);
    }
#pragma unroll
    for (int p = 0; p < 4; ++p) {  // stage sWt: 16 ch x 64 out = 1024
      int e = tid + (p << 8);
      int cc = e >> 6, xx = e & 63;
      sWt[e] = wslt[((c0 + cc) << 6) + xx];
    }
    __syncthreads();
#pragma unroll
    for (int cc = 0; cc < 16; ++cc) {
      float hv = sH[cc * 17 + x4];
      float4 w0 = *(const float4*)&sWt[(cc << 6) + (og << 2)];
      acc[0] = fmaf(hv, w0.x, acc[0]);
      acc[1] = fmaf(hv, w0.y, acc[1]);
      acc[2] = fmaf(hv, w0.z, acc[2]);
      acc[3] = fmaf(hv, w0.w, acc[3]);
    }
  }
  __syncthreads();
#pragma unroll
  for (int j = 0; j < 4; ++j) {
    int o = (og << 2) + j;
    sOut[o * 17 + x4] = acc[j] + wslb[o];
  }
  __syncthreads();

  const int p0 = (n << 12) + (y << 6);
  float* locs = out + O0 + (size_t)p0 * 36 + (size_t)x0 * 36;
  for (int e = tid; e < 576; e += 256) {
    int xx = e / 36, o = e - xx * 36;
    locs[e] = sOut[o * 17 + xx];
  }
  float* scrs = out + O1 + (size_t)p0 * 18 + (size_t)x0 * 18;
  for (int e = tid; e < 288; e += 256) {
    int xx = e / 18, ss = e - xx * 18;
    scrs[e] = sOut[(36 + ss) * 17 + xx];
  }
  float* fg = fgbuf + n * NANCH + ((y << 6) + x0) * 9;
  for (int e = tid; e < 144; e += 256) {
    int xx = e / 9, a = e - xx * 9;
    float s0 = sOut[(36 + 2 * a) * 17 + xx];
    float s1 = sOut[(36 + 2 * a + 1) * 17 + xx];
    fg[e] = 1.0f / (1.0f + expf(s0 - s1));
  }
}

// ---------------------------------------------------------------------------
// 3. anchors + decode + clip + min-size + sort keys + FUSED histogram.
// R13: histogram back to 65536 bins (hk>>16) — R12's 4096-bin version
// broke the CAP invariant (sigmoid scores concentrate; a 12-bit tie-bin
// can exceed CAP-6000 slack -> arbitrary key drops -> wrong top-6000).
// Pre-inits cbuf/sbox/alive/rankbuf/cnt[0..3].
// ---------------------------------------------------------------------------
__global__ __launch_bounds__(256) void decode_kernel(
    const float* __restrict__ out0, const float* __restrict__ fgbuf,
    float4* __restrict__ roibuf, u64* __restrict__ keys,
    float* __restrict__ anchor_out, float* __restrict__ out,
    u32* __restrict__ hist, u64* __restrict__ cbuf,
    float4* __restrict__ sbox, u64* __restrict__ alive,
    u32* __restrict__ rankbuf, u32* __restrict__ cnt,
    const int* __restrict__ imgh_p, const int* __restrict__ imgw_p) {
  int gid = blockIdx.x * 256 + threadIdx.x;   // < 131072
  if (gid < 16384) { cbuf[gid] = ~0ull; rankbuf[gid] = 0u; }
  if (gid < 12288) sbox[gid] = make_float4(0.f, 0.f, 0.f, 0.f);
  if (gid < 192) alive[gid] = 0ull;
  if (gid < 4) cnt[gid] = 0u;
  if (gid < 3600) {
    if (gid < 2400) out[O2 + gid] = 0.f;
    else if (gid < 3000) out[O3 + (gid - 2400)] = (float)((gid - 2400) / 300);
    else out[O5 + (gid - 3000)] = 0.f;
  }
  int n = gid >> 16, k = gid & (SEG - 1);
  if (k >= NANCH) return;
  int a = k % 9;
  int p = k / 9;
  int py = p >> 6, px = p & 63;

  const double R[3] = {0.5, 1.0, 2.0};
  const double S[3] = {8.0, 16.0, 32.0};
  double r = R[a / 3], s = S[a - (a / 3) * 3];
  double hd = 16.0 * s * sqrt(r);
  double wd = 16.0 * s * sqrt(1.0 / r);
  float ay1 = (float)(8.0 - hd / 2.0) + (float)(py * 16);
  float ax1 = (float)(8.0 - wd / 2.0) + (float)(px * 16);
  float ay2 = (float)(8.0 + hd / 2.0) + (float)(py * 16);
  float ax2 = (float)(8.0 + wd / 2.0) + (float)(px * 16);
  if (n == 0) {
    *(float4*)(anchor_out + ((size_t)k << 2)) = make_float4(ay1, ax1, ay2, ax2);
  }
  float ahk = ay2 - ay1, awk = ax2 - ax1;
  float acy = ay1 + 0.5f * ahk, acx = ax1 + 0.5f * awk;
  float4 lv = *(const float4*)(out0 + ((size_t)(n * NANCH + k) << 2));
  float dy = lv.x, dx = lv.y, dh = lv.z, dw = lv.w;
  float cy = dy * ahk + acy;
  float cx = dx * awk + acx;
  float bh = expf(dh) * ahk;
  float bw = expf(dw) * awk;
  float img_h = (float)imgh_p[0], img_w = (float)imgw_p[0];
  float y1 = fminf(fmaxf(cy - 0.5f * bh, 0.f), img_h);
  float x1 = fminf(fmaxf(cx - 0.5f * bw, 0.f), img_w);
  float y2 = fminf(fmaxf(cy + 0.5f * bh, 0.f), img_h);
  float x2 = fminf(fmaxf(cx + 0.5f * bw, 0.f), img_w);
  bool valid = ((y2 - y1) >= 16.f) && ((x2 - x1) >= 16.f);
  float sc = valid ? fgbuf[n * NANCH + k] : -INFINITY;
  roibuf[n * NANCH + k] = make_float4(y1, x1, y2, x2);
  unsigned int b = __float_as_uint(sc);
  unsigned int m = b ^ ((b & 0x80000000u) ? 0xFFFFFFFFu : 0x80000000u);
  u32 hk = ~m;
  keys[gid] = ((u64)hk << 32) | (unsigned int)k;
  if (hk < 0xFF800000u) atomicAdd(&hist[(n << 16) + (hk >> 16)], 1u);
}

// ---------------------------------------------------------------------------
// 4a. threshold: 65536-bin scan -> rank-6000 bin T in cnt[2+n]. 1 block of
// 1024 per image (R4-proven structure, R11 register bin-walk). T stays 0
// when no valid keys — nothing passes the validity check downstream.
// ---------------------------------------------------------------------------
__global__ __launch_bounds__(1024) void thresh_kernel(
    const u32* __restrict__ hist, u32* __restrict__ cnt) {
  const int n = blockIdx.x, t = threadIdx.x;
  __shared__ u32 sc_[1064];
  const uint4* hp = (const uint4*)(hist + (n << 16));
  u32 s = 0;
#pragma unroll
  for (int q = 0; q < 16; ++q) {
    uint4 v = hp[t * 16 + q];
    s += v.x + v.y + v.z + v.w;
  }
  sc_[SCX(t)] = s;
  __syncthreads();
  for (int off = 1; off < 1024; off <<= 1) {
    u32 v = (t >= off) ? sc_[SCX(t - off)] : 0u;
    __syncthreads();
    sc_[SCX(t)] += v;
    __syncthreads();
  }
  u32 total = sc_[SCX(1023)];
  u32 target = total < (u32)N_PRE ? total : (u32)N_PRE;
  u32 mycum = sc_[SCX(t)];
  u32 prev = t ? sc_[SCX(t - 1)] : 0u;
  if (total > 0 && mycum >= target && prev < target) {
    u32 binv[64];
#pragma unroll
    for (int q = 0; q < 16; ++q) {      // 16 independent loads, one wait
      uint4 v = hp[t * 16 + q];
      binv[4 * q + 0] = v.x; binv[4 * q + 1] = v.y;
      binv[4 * q + 2] = v.z; binv[4 * q + 3] = v.w;
    }
    u32 base = prev, bsel = 0u;
    bool found = false;
#pragma unroll
    for (int j = 0; j < 64; ++j) {
      if (!found) {
        base += binv[j];
        if (base >= target) { bsel = (u32)((t << 6) + j); found = true; }
      }
    }
    cnt[2 + n] = bsel;
  }
}

// ---------------------------------------------------------------------------
// 4b. compact: grid (18,2) — each block compacts its 2048-key slice with
// wave-aggregated global atomicAdd slot allocation (parallelizes the 1MB
// key stream across 36 blocks; was 2 blocks). cbuf order is arbitrary but
// rank_scatter orders by rank — identical final outputs.
// ---------------------------------------------------------------------------
__global__ __launch_bounds__(256) void compact_kernel(
    const u64* __restrict__ keys, u64* __restrict__ cbuf,
    u32* __restrict__ cnt) {
  const int n = blockIdx.y, t = threadIdx.x;
  const u32 T = cnt[2 + n];
  const int lane = t & 63;
  const u64 below = lane ? (~0ull >> (64 - lane)) : 0ull;
  const int i0 = blockIdx.x * 2048;
  for (int i = i0 + t; i < i0 + 2048; i += 256) {
    u64 key = keys[(n << 16) + i];
    u32 hk = (u32)(key >> 32);
    bool take = hk < 0xFF800000u && (hk >> 16) <= T;
    u64 bal = __ballot(take);
    u32 base = 0;
    if (lane == 0 && bal) base = atomicAdd(&cnt[n], (u32)__popcll(bal));
    base = (u32)__shfl((int)base, 0);
    if (take) {
      u32 slot = base + (u32)__popcll(bal & below);
      if (slot < (u32)CAP) cbuf[(n << 13) + slot] = key;
    }
  }
}

// ---------------------------------------------------------------------------
// 4c. rank-by-counting, J-SPLIT. Partial ranks over 1024-key chunks on
// 512 blocks (2/CU, full GPU), atomicAdd into pre-zeroed rankbuf.
// rank[i] = #{j: key_j < key_i}; keys unique -> rank == sorted position.
// ---------------------------------------------------------------------------
#define JTILE 1024
__global__ __launch_bounds__(256) void rank_partial(
    const u64* __restrict__ cbuf, u32* __restrict__ rankbuf) {
  __shared__ u64 lk[JTILE];
  const int n = blockIdx.z;
  const int i = blockIdx.x * 256 + threadIdx.x;    // 0..8191
  const int j0 = blockIdx.y * JTILE;
  const u64* cb = cbuf + (n << 13);
  const u64 mykey = cb[i];
  for (int e = threadIdx.x; e < JTILE; e += 256) lk[e] = cb[j0 + e];
  __syncthreads();
  u32 r = 0;
#pragma unroll 8
  for (int j = 0; j < JTILE; ++j) r += (lk[j] < mykey) ? 1u : 0u;
  atomicAdd(&rankbuf[(n << 13) + i], r);
}

// ---------------------------------------------------------------------------
// 4d. scatter by rank: sbox[rank] = box, alive bit rank (rank < 6000).
// ---------------------------------------------------------------------------
__global__ __launch_bounds__(256) void rank_scatter(
    const u64* __restrict__ cbuf, const u32* __restrict__ rankbuf,
    const float4* __restrict__ roibuf,
    float4* __restrict__ sbox, u64* __restrict__ alive) {
  const int n = blockIdx.y;
  const int i = blockIdx.x * 256 + threadIdx.x;    // 0..8191
  u64 mykey = cbuf[(n << 13) + i];
  if (mykey == ~0ull) return;
  u32 rank = rankbuf[(n << 13) + i];
  if (rank < (u32)N_PRE) {
    u32 k = (u32)(mykey & 0xFFFFFFFFull);
    sbox[n * NPADC + rank] = roibuf[(size_t)n * NANCH + k];
    atomicOr(&alive[n * NW + (rank >> 6)], 1ull << (rank & 63));
  }
}

// ---------------------------------------------------------------------------
// 6b. build suppression matrix — UPPER-TRIANGLE only (w >= g).
// ---------------------------------------------------------------------------
__global__ __launch_bounds__(256) void build_mask(
    const float4* __restrict__ sbox, u64* __restrict__ M) {
  __shared__ float4 jb[4][64];
  __shared__ float ja[4][64];
  const int tid = threadIdx.x, lane = tid & 63, wv = tid >> 6;
  const int g = blockIdx.x, q = blockIdx.y, n = blockIdx.z;
  const float4* sb = sbox + n * NPADC;
  float4 bi = sb[(g << 6) + lane];
  float ai = (bi.z - bi.x) * (bi.w - bi.y);
  u64* Mrow = M + ((size_t)(n * NPADC + (g << 6) + lane)) * NW;
#pragma unroll
  for (int it = 0; it < 6; ++it) {
    int w = q * 24 + (it << 2) + wv;
    if (w < g) continue;                 // dead lower-triangle word
    float4 bjl = sb[(w << 6) + lane];
    jb[wv][lane] = bjl;
    ja[wv][lane] = (bjl.z - bjl.x) * (bjl.w - bjl.y);
    u64 bits = 0;
#pragma unroll 8
    for (int j = 0; j < 64; ++j) {
      float4 bj = jb[wv][j];
      float aj = ja[wv][j];
      float ih = fmaxf(fminf(bi.z, bj.z) - fmaxf(bi.x, bj.x), 0.f);
      float iw = fmaxf(fminf(bi.w, bj.w) - fmaxf(bi.y, bj.y), 0.f);
      float inter = ih * iw;
      bool bit = inter / (ai + aj - inter + 1e-9f) > 0.7f;
      bits |= ((u64)bit) << j;
    }
    Mrow[w] = bits;
  }
}

// ---------------------------------------------------------------------------
// 6c. parallel greedy reduce. 1024 threads per image. Serial greedy ballot
// on wave 0; kept-row OR accumulation on threads [256,1024) as a 96-word x
// 8-row-slot grid (one parallel load batch per chunk) into an LDS
// accumulator. Identical decisions/order to the serial version.
// ---------------------------------------------------------------------------
__global__ __launch_bounds__(1024) void nms_reduce(
    const u64* __restrict__ M, const u64* __restrict__ alive,
    const float4* __restrict__ sbox, float* __restrict__ out) {
  const int n = blockIdx.x, t = threadIdx.x;
  const int lane = t & 63, wv = t >> 6;
  float* rois = out + O2 + n * (N_POST * 4);
  float* vmask = out + O5 + n * N_POST;
  const u64* A = alive + n * NW;
  const u64* Mb = M + (size_t)n * NPADC * NW;
  const float4* sb = sbox + n * NPADC;

  __shared__ u64 accLds[NW];      // suppressed-mask accumulator
  __shared__ int rowsS[64];       // kept-row list for the OR threads
  __shared__ int cntS;
  __shared__ int doneS;

  if (t < NW) accLds[t] = 0ull;
  if (t == 0) { doneS = 0; cntS = 0; }

  // wave-0 private greedy state
  u64 aw0 = 0, aw1 = 0;
  u64 dnext = 0;
  float4 bnext = make_float4(0.f, 0.f, 0.f, 0.f);
  int nk = 0;
  const u64 below = lane ? (~0ull >> (64 - lane)) : 0ull;
  if (wv == 0) {
    aw0 = A[lane];
    aw1 = (lane < 32) ? A[64 + lane] : 0ull;
    dnext = Mb[(size_t)lane * NW + 0];
    bnext = sb[lane];
  }

  // OR-thread mapping: threads [256,1024) -> 96 words x 8 row-slots
  const int u = t - 256;
  const int word = (u >= 0) ? (u % 96) : 0;
  const int slot = (u >= 0) ? (u / 96) : 0;

  __syncthreads();

  for (int c = 0; c < 94; ++c) {
    if (wv == 0) {
      u64 dcur = dnext;
      float4 bcur = bnext;
      if (c + 1 < 94) {
        dnext = Mb[(size_t)(((c + 1) << 6) + lane) * NW + (c + 1)];
        bnext = sb[((c + 1) << 6) + lane];
      }
      u64 wacc = accLds[c];                        // LDS broadcast
      u64 aw = (c < 64) ? bcast64(aw0, c) : bcast64(aw1, c - 64);
      u64 alive_u = aw & ~wacc;
      u64 kept = 0;
      if (alive_u) {
        u64 dmask = dcur & below;
        u64 rem = alive_u;
        while (rem) {
          int j = __builtin_ctzll(rem);            // uniform across wave
          kept |= 1ull << j;
          u64 col = __ballot((dmask >> j) & 1);
          rem &= ~(col | (1ull << j));
        }
        int npop = __popcll(kept);
        if ((kept >> lane) & 1ull) {
          int oslot = nk + __popcll(kept & below);
          if (oslot < N_POST) {
            rois[oslot * 4 + 0] = bcur.x; rois[oslot * 4 + 1] = bcur.y;
            rois[oslot * 4 + 2] = bcur.z; rois[oslot * 4 + 3] = bcur.w;
            vmask[oslot] = 1.0f;
          }
          rowsS[__popcll(kept & below)] = (c << 6) + lane;
        }
        if (lane == 0) {
          cntS = npop;
          if (nk + npop >= N_POST) doneS = 1;
        }
        nk += npop;
      } else {
        if (lane == 0) cntS = 0;
      }
    }
    __syncthreads();                 // rowsS/cntS/doneS visible; prev OR done
    if (doneS) break;                // matches serial: break skips the OR
    const int cnt = cntS;
    if (cnt > 0 && u >= 0) {
      int b0 = slot << 3;            // this slot's 8 rows of the kept list
      if (b0 < cnt) {
        int i1 = (b0 + 1 < cnt) ? b0 + 1 : cnt - 1;
        int i2 = (b0 + 2 < cnt) ? b0 + 2 : cnt - 1;
        int i3 = (b0 + 3 < cnt) ? b0 + 3 : cnt - 1;
        int i4 = (b0 + 4 < cnt) ? b0 + 4 : cnt - 1;
        int i5 = (b0 + 5 < cnt) ? b0 + 5 : cnt - 1;
        int i6 = (b0 + 6 < cnt) ? b0 + 6 : cnt - 1;
        int i7 = (b0 + 7 < cnt) ? b0 + 7 : cnt - 1;
        const u64* r0 = Mb + (size_t)rowsS[b0] * NW;
        const u64* r1 = Mb + (size_t)rowsS[i1] * NW;
        const u64* r2 = Mb + (size_t)rowsS[i2] * NW;
        const u64* r3 = Mb + (size_t)rowsS[i3] * NW;
        const u64* r4 = Mb + (size_t)rowsS[i4] * NW;
        const u64* r5 = Mb + (size_t)rowsS[i5] * NW;
        const u64* r6 = Mb + (size_t)rowsS[i6] * NW;
        const u64* r7 = Mb + (size_t)rowsS[i7] * NW;
        u64 p = r0[word] | r1[word] | r2[word] | r3[word]
              | r4[word] | r5[word] | r6[word] | r7[word];
        atomicOr(&accLds[word], p);
      }
    }
    __syncthreads();                 // acc updated before next chunk's read
  }
}

// ---------------------------------------------------------------------------
extern "C" void kernel_launch(void* const* d_in, const int* in_sizes, int n_in,
                              void* d_out, int out_size, void* d_ws, size_t ws_size,
                              hipStream_t stream) {
  const float* x        = (const float*)d_in[0];
  const float* conv1_w  = (const float*)d_in[1];
  const float* conv1_b  = (const float*)d_in[2];
  const float* score_w  = (const float*)d_in[3];
  const float* score_b  = (const float*)d_in[4];
  const float* loc_w    = (const float*)d_in[5];
  const float* loc_b    = (const float*)d_in[6];
  const int*   imgh_p   = (const int*)d_in[7];
  const int*   imgw_p   = (const int*)d_in[8];

  float* out = (float*)d_out;
  float* ws  = (float*)d_ws;

  _Float16* xhi = (_Float16*)(ws + WS_XHI);
  _Float16* xlo = (_Float16*)(ws + WS_XLO);
  _Float16* whi = (_Float16*)(ws + WS_WHI);
  _Float16* wlo = (_Float16*)(ws + WS_WLO);
  float* wslt   = ws + WS_WSLT;
  float* wslb   = ws + WS_WSLB;
  float* hbuf   = ws + WS_H;
  float* guard  = ws + WS_GUARD;
  // overlays (xhi region is dead after conv)
  float* fgbuf   = ws + WS_FG;
  float4* roibuf = (float4*)(ws + WS_ROI);
  u64* keys      = (u64*)(ws + WS_KEYS);
  float4* sbox   = (float4*)(ws + WS_SBOX);
  u64* alive     = (u64*)(ws + WS_ALIVE);
  u64* cbuf      = (u64*)(ws + WS_CBUF);
  u32* hist      = (u32*)(ws + WS_HIST);
  u32* rankbuf   = (u32*)(ws + WS_RANK);
  u32* cnt       = (u32*)(ws + WS_CNT);
  u64* maskbuf   = (u64*)(ws + WS_MASK);   // overlays whi/wlo (dead after conv)

  prep_all<<<5506, 256, 0, stream>>>(x, conv1_w, loc_w, score_w, loc_b, score_b,
                                     (float4*)hbuf, (float4*)guard,
                                     xhi, xlo, whi, wlo, wslt, wslb);

  conv_mfma<<<dim3(64, 4, 2), 256, 0, stream>>>(xhi, xlo, whi, wlo, guard, hbuf);

  head_kernel<<<dim3(64, 2, 4), 256, 0, stream>>>(hbuf, conv1_b, wslt, wslb, out,
                                                  fgbuf, (uint4*)hist);
  decode_kernel<<<512, 256, 0, stream>>>(out, fgbuf, roibuf, keys,
                                         out + O4, out, hist, cbuf, sbox, alive,
                                         rankbuf, cnt, imgh_p, imgw_p);

  thresh_kernel<<<2, 1024, 0, stream>>>(hist, cnt);
  compact_kernel<<<dim3(18, 2), 256, 0, stream>>>(keys, cbuf, cnt);
  rank_partial<<<dim3(32, 8, 2), 256, 0, stream>>>(cbuf, rankbuf);
  rank_scatter<<<dim3(32, 2), 256, 0, stream>>>(cbuf, rankbuf, roibuf, sbox, alive);

  build_mask<<<dim3(96, 4, 2), 256, 0, stream>>>(sbox, maskbuf);
  nms_reduce<<<2, 1024, 0, stream>>>(maskbuf, alive, sbox, out);
}

// Round 14
// 417.599 us; speedup vs baseline: 1.0155x; 1.0155x over previous
//
#include <hip/hip_runtime.h>
#include <hip/hip_bf16.h>
#include <math.h>
#include <cstdint>

typedef unsigned long long u64;
typedef unsigned int u32;
typedef _Float16 half8 __attribute__((ext_vector_type(8)));
typedef _Float16 half4 __attribute__((ext_vector_type(4)));
typedef _Float16 half2t __attribute__((ext_vector_type(2)));
typedef float floatx4 __attribute__((ext_vector_type(4)));

// ---------------------------------------------------------------------------
// Sizes
// ---------------------------------------------------------------------------
#define NANCH 36864        // 4096*9
#define SEG 65536          // per-image key segment stride (layout only)
#define N_PRE 6000
#define N_POST 300
#define NW 96              // mask words per row (6144 bits)
#define NPADC 6144         // padded candidate count
#define CAP 8192           // compaction buffer capacity per image

// output float offsets
#define O0 0               // rpn_locs  2*36864*4 = 294912
#define O1 294912          // rpn_scores 2*36864*2 = 147456
#define O2 442368          // rois 2*300*4 = 2400
#define O3 444768          // roi_indices 600
#define O4 445368          // anchor 147456
#define O5 592824          // vmask 600

// workspace float offsets
#define WS_XHI   0                        // xhi f16 [2][4096][512] (2,097,152 f)
#define WS_XLO   2097152
#define WS_WHI   4194304                  // whi f16 [9][512][512] (1,179,648 f)
#define WS_WLO   5373952
#define WS_WSLT  6553600                  // 32768
#define WS_WSLB  6586368                  // 64
#define WS_H     6586432                  // hbuf f32 [2][4096][512] = 4,194,304 f
#define WS_GUARD 10780736                 // 64 floats of zeros (OOB target)
// overlays into dead XHI region (used only after conv completes):
#define WS_FG    0                        // 73728
#define WS_ROI   73728                    // 294912 (16B aligned)
#define WS_KEYS  368640                   // 131072 u64 = 262144 f
#define WS_SBOX  630784                   // 2*6144 float4 = 49152 f
#define WS_ALIVE 679936                   // 2*96 u64 = 384 f
#define WS_CBUF  680320                   // 2*8192 u64 = 32768 f (ends at WS_HIST)
#define WS_HIST  713088                   // 2*65536 u32 = 131072 f
#define WS_RANK  844160                   // 2*8192 u32 = 16384 f
#define WS_CNT   860544                   // [0,1]=cnt
// overlay into dead WHI+WLO region (after conv): FULL suppression matrix
#define WS_MASK  4194304                  // 2*6144*96 u64 = 9,437,184 B (exact fit)

#define HSCALE 9.5367431640625e-07f       // 2^-20

// ---------------------------------------------------------------------------
__device__ __forceinline__ void gl_lds16(const void* g, void* l) {
  __builtin_amdgcn_global_load_lds(
      (const __attribute__((address_space(1))) u32*)g,
      (__attribute__((address_space(3))) u32*)l, 16, 0, 0);
}

__device__ __forceinline__ u64 bcast64(u64 v, int src) {
  u32 lo = (u32)__shfl((int)(v & 0xFFFFFFFFull), src);
  u32 hi = (u32)__shfl((int)(v >> 32), src);
  return ((u64)hi << 32) | lo;
}

// padded u32 index for scans (stride-2^k accesses)
__device__ __forceinline__ int SCX(int t) { return t + (t >> 5); }

// ---------------------------------------------------------------------------
// 0. fused prep: zero hbuf+guard | xcvt | wcvt | head-weight pack.
// Grid: [0,4097) zero | [4097,5121) xcvt | [5121,5377) wcvt | [5377,5506) small.
// ---------------------------------------------------------------------------
__global__ __launch_bounds__(256) void prep_all(
    const float* __restrict__ x, const float* __restrict__ w,
    const float* __restrict__ lw, const float* __restrict__ sw,
    const float* __restrict__ lb, const float* __restrict__ sb,
    float4* __restrict__ h, float4* __restrict__ guard,
    _Float16* __restrict__ xhi, _Float16* __restrict__ xlo,
    _Float16* __restrict__ whi, _Float16* __restrict__ wlo,
    float* __restrict__ wslt, float* __restrict__ wslb) {
  const int b = blockIdx.x, tid = threadIdx.x;
  if (b < 4097) {
    int idx = b * 256 + tid;
    if (idx < 1048576) h[idx] = make_float4(0.f, 0.f, 0.f, 0.f);
    else if (idx < 1048576 + 16) guard[idx - 1048576] = make_float4(0.f, 0.f, 0.f, 0.f);
    return;
  }
  if (b < 5121) {  // xcvt: [n][c][pix] f32 -> [n][pix][c] f16 hi/lo x1024
    __shared__ float s[64 * 65];
    int l = b - 4097;
    int pt = l & 63, cg = (l >> 6) & 7, n = l >> 9;
    const int c0 = cg << 6, p0 = pt << 6;
#pragma unroll
    for (int kk = 0; kk < 4; ++kk) {   // 1024 float4 loads: 64 ci x 16 quads
      int e = tid + (kk << 8);
      int ci = e >> 4, pi = (e & 15) << 2;
      float4 v = *(const float4*)&x[(((size_t)(n * 512 + c0 + ci)) << 12) + p0 + pi];
      s[ci * 65 + pi + 0] = v.x;
      s[ci * 65 + pi + 1] = v.y;
      s[ci * 65 + pi + 2] = v.z;
      s[ci * 65 + pi + 3] = v.w;
    }
    __syncthreads();
#pragma unroll
    for (int kk = 0; kk < 4; ++kk) {   // 1024 quads: 64 pi x 16 ci-quads
      int e = tid + (kk << 8);
      int pi = e >> 4, ci = (e & 15) << 2;
      half4 hv, lv;
#pragma unroll
      for (int j = 0; j < 4; ++j) {
        float sv = s[(ci + j) * 65 + pi] * 1024.f;
        _Float16 hi = (_Float16)sv;
        hv[j] = hi;
        lv[j] = (_Float16)(sv - (float)hi);
      }
      size_t off = (((size_t)(n << 12) + p0 + pi) << 9) + c0 + ci;
      *(half4*)(xhi + off) = hv;
      *(half4*)(xlo + off) = lv;
    }
    return;
  }
  if (b < 5377) {  // wcvt: [o][c][3][3] -> [t][o][c] f16 hi/lo x1024
    __shared__ float sw_[16 * 584];    // 16 o-rows x 576 (+8 pad) = 37.4 KB
    int l = b - 5121;                  // 0..255
    int ot = l >> 3, ct = l & 7;       // 32 o-tiles(16) x 8 c-tiles(64)
    const int o0 = ot << 4, c0 = ct << 6;
    for (int e = tid; e < 9216; e += 256) {   // coalesced slab read
      int r = e / 576, j = e - r * 576;
      sw_[r * 584 + j] = w[(size_t)(o0 + r) * 4608 + (size_t)c0 * 9 + j];
    }
    __syncthreads();
    for (int e = tid; e < 4608; e += 256) {   // pairs (t, r, ci-even)
      int t = e / 512, rem = e - t * 512;
      int r = rem >> 5, cp = rem & 31, ci = cp << 1;
      float v0 = sw_[r * 584 + ci * 9 + t] * 1024.f;
      float v1 = sw_[r * 584 + (ci + 1) * 9 + t] * 1024.f;
      _Float16 h0 = (_Float16)v0, h1 = (_Float16)v1;
      half2t hh = {h0, h1};
      half2t ll = {(_Float16)(v0 - (float)h0), (_Float16)(v1 - (float)h1)};
      size_t off = ((size_t)((t << 9) + o0 + r) << 9) + c0 + ci;
      *(half2t*)(whi + off) = hh;
      *(half2t*)(wlo + off) = ll;
    }
    return;
  }
  {  // prep_small
    int e = (b - 5377) * 256 + tid;
    if (e < 32768) {
      int c = e >> 6, o = e & 63;
      float v = 0.f;
      if (o < 36) v = lw[o * 512 + c];
      else if (o < 54) v = sw[(o - 36) * 512 + c];
      wslt[e] = v;
    } else if (e < 32832) {
      int o = e - 32768;
      float v = 0.f;
      if (o < 36) v = lb[o];
      else if (o < 54) v = sb[o - 36];
      wslb[o] = v;
    }
  }
}

// ---------------------------------------------------------------------------
// 1. MFMA implicit-GEMM 3x3 conv (fp16x2 split: hh + hl + lh, fp32 acc).
// R0 structure, parked: 121us = ~960 TF effective on the 3-pass GEMM —
// at the plain-HIP 2-barrier-structure ceiling (m97/m103). Perturbations
// all regressed: R1 pipelined dbuf 129 | R2 pass-split 217 | R3 B-in-regs
// 169. Do not touch.
// ---------------------------------------------------------------------------
__global__ __launch_bounds__(256) void conv_mfma(
    const _Float16* __restrict__ xhi, const _Float16* __restrict__ xlo,
    const _Float16* __restrict__ whi, const _Float16* __restrict__ wlo,
    const float* __restrict__ guard, float* __restrict__ hout) {
  __shared__ _Float16 aHi[4 * 68 * 32];
  __shared__ _Float16 aLo[4 * 68 * 32];
  __shared__ _Float16 bHi[128 * 32];
  __shared__ _Float16 bLo[128 * 32];
  const int tid = threadIdx.x;
  const int lane = tid & 63, w = tid >> 6;
  const int ptile = blockIdx.x;
  const int og = blockIdx.y;
  const int kq = blockIdx.z;
  const int n = ptile >> 5;
  const int y0 = (ptile & 31) << 1;
  const int o0 = og << 7;
  const int l15 = lane & 15, l16 = lane >> 4;
  const int ry = w >> 1;
  const int wo = (w & 1) << 6;

  floatx4 acc[4][4];
#pragma unroll
  for (int a = 0; a < 4; ++a)
#pragma unroll
    for (int b = 0; b < 4; ++b) acc[a][b] = (floatx4)0.f;

  for (int s = 0; s < 8; ++s) {
    const int c0 = (kq << 8) + (s << 5);
    __syncthreads();
    for (int i = w; i < 17; i += 4) {
      int chunk = (i << 6) + lane;
      int p = chunk >> 2, q = chunk & 3;
      int r = p / 68, xs = p - r * 68;
      int y = y0 - 1 + r, xg = xs - 1;
      bool ok = ((unsigned)y < 64u) && ((unsigned)xg < 64u);
      size_t off = (((size_t)(n << 12) + (y << 6) + xg) << 9) + c0 + (q << 3);
      const void* gh = ok ? (const void*)(xhi + off) : (const void*)guard;
      const void* gl = ok ? (const void*)(xlo + off) : (const void*)guard;
      gl_lds16(gh, (char*)aHi + (i << 10));
      gl_lds16(gl, (char*)aLo + (i << 10));
    }
    for (int tt = 0; tt < 9; ++tt) {
      if (tt > 0) __syncthreads();
      for (int i = w; i < 8; i += 4) {
        int chunk = (i << 6) + lane;
        int row = chunk >> 2, q = chunk & 3;
        size_t off = ((size_t)((tt << 9) + o0 + row) << 9) + c0 + (q << 3);
        gl_lds16((const void*)(whi + off), (char*)bHi + (i << 10));
        gl_lds16((const void*)(wlo + off), (char*)bLo + (i << 10));
      }
      __syncthreads();

      const int dy = tt / 3, dx = tt - 3 * dy;
      half8 ah[4], al[4], bh[4], bl[4];
#pragma unroll
      for (int im = 0; im < 4; ++im) {
        int xp = (im << 4) + l15;
        int p = (ry + dy) * 68 + xp + dx;
        ah[im] = *(const half8*)&aHi[(p << 5) + (l16 << 3)];
        al[im] = *(const half8*)&aLo[(p << 5) + (l16 << 3)];
      }
#pragma unroll
      for (int in = 0; in < 4; ++in) {
        int orow = wo + (in << 4) + l15;
        bh[in] = *(const half8*)&bHi[(orow << 5) + (l16 << 3)];
        bl[in] = *(const half8*)&bLo[(orow << 5) + (l16 << 3)];
      }
#pragma unroll
      for (int im = 0; im < 4; ++im)
#pragma unroll
        for (int in = 0; in < 4; ++in) {
          acc[im][in] = __builtin_amdgcn_mfma_f32_16x16x32_f16(
              ah[im], bh[in], acc[im][in], 0, 0, 0);
          acc[im][in] = __builtin_amdgcn_mfma_f32_16x16x32_f16(
              ah[im], bl[in], acc[im][in], 0, 0, 0);
          acc[im][in] = __builtin_amdgcn_mfma_f32_16x16x32_f16(
              al[im], bh[in], acc[im][in], 0, 0, 0);
        }
    }
  }

#pragma unroll
  for (int im = 0; im < 4; ++im)
#pragma unroll
    for (int in = 0; in < 4; ++in) {
      int o = o0 + wo + (in << 4) + l15;
#pragma unroll
      for (int reg = 0; reg < 4; ++reg) {
        int m_local = (ry << 6) + (im << 4) + (l16 << 2) + reg;
        size_t off = (((size_t)(n << 12) + (y0 << 6) + m_local) << 9) + o;
        atomicAdd(&hout[off], acc[im][in][reg]);
      }
    }
}

// ---------------------------------------------------------------------------
// 2. 1x1 heads + softmax. grid (64 y, 2 n, 4 xq), block 256.
// ---------------------------------------------------------------------------
__global__ __launch_bounds__(256) void head_kernel(
    const float* __restrict__ hbuf, const float* __restrict__ cb,
    const float* __restrict__ wslt, const float* __restrict__ wslb,
    float* __restrict__ out, float* __restrict__ fgbuf,
    uint4* __restrict__ hist4) {
  const int y = blockIdx.x, n = blockIdx.y, xq = blockIdx.z;
  __shared__ float sH[16 * 17];
  __shared__ float sWt[1024];
  __shared__ float sOut[64 * 17];
  const int tid = threadIdx.x;
  const int x4 = tid & 15, og = tid >> 4;   // 16 x-positions, 16 out-groups
  const int x0 = xq << 4;                    // x-quarter base

  // init for the selection path (xq==0 blocks: 128 x 256 = 32768 lanes)
  if (xq == 0) {
    int gid = ((n << 6) + y) * 256 + tid;          // 0..32767
    hist4[gid] = make_uint4(0u, 0u, 0u, 0u);       // 512 KB = full hist
  }

  float acc[4];
#pragma unroll
  for (int j = 0; j < 4; ++j) acc[j] = 0.f;

  const float* hb = hbuf + (((size_t)(n << 12) + (y << 6) + x0) << 9);

  for (int c0 = 0; c0 < 512; c0 += 16) {
    __syncthreads();
    {  // stage sH: 16 ch x 16 x = 256 elems (1/thread)
      int cc = tid & 15, xx = tid >> 4;
      float raw = hb[((size_t)xx << 9) + c0 + cc];
      sH[cc * 17 + xx] = fmaxf(raw * HSCALE + cb[c0 + cc], 0.f);
    }
#pragma unroll
    for (int p = 0; p < 4; ++p) {  // stage sWt: 16 ch x 64 out = 1024
      int e = tid + (p << 8);
      int cc = e >> 6, xx = e & 63;
      sWt[e] = wslt[((c0 + cc) << 6) + xx];
    }
    __syncthreads();
#pragma unroll
    for (int cc = 0; cc < 16; ++cc) {
      float hv = sH[cc * 17 + x4];
      float4 w0 = *(const float4*)&sWt[(cc << 6) + (og << 2)];
      acc[0] = fmaf(hv, w0.x, acc[0]);
      acc[1] = fmaf(hv, w0.y, acc[1]);
      acc[2] = fmaf(hv, w0.z, acc[2]);
      acc[3] = fmaf(hv, w0.w, acc[3]);
    }
  }
  __syncthreads();
#pragma unroll
  for (int j = 0; j < 4; ++j) {
    int o = (og << 2) + j;
    sOut[o * 17 + x4] = acc[j] + wslb[o];
  }
  __syncthreads();

  const int p0 = (n << 12) + (y << 6);
  float* locs = out + O0 + (size_t)p0 * 36 + (size_t)x0 * 36;
  for (int e = tid; e < 576; e += 256) {
    int xx = e / 36, o = e - xx * 36;
    locs[e] = sOut[o * 17 + xx];
  }
  float* scrs = out + O1 + (size_t)p0 * 18 + (size_t)x0 * 18;
  for (int e = tid; e < 288; e += 256) {
    int xx = e / 18, ss = e - xx * 18;
    scrs[e] = sOut[(36 + ss) * 17 + xx];
  }
  float* fg = fgbuf + n * NANCH + ((y << 6) + x0) * 9;
  for (int e = tid; e < 144; e += 256) {
    int xx = e / 9, a = e - xx * 9;
    float s0 = sOut[(36 + 2 * a) * 17 + xx];
    float s1 = sOut[(36 + 2 * a + 1) * 17 + xx];
    fg[e] = 1.0f / (1.0f + expf(s0 - s1));
  }
}

// ---------------------------------------------------------------------------
// 3. anchors + decode + clip + min-size + sort keys + FUSED histogram
// (65536 bins, hk>>16 — 16-bit binning is required for the CAP invariant;
// R12's 12-bit version dropped true top-6000 keys).
// Pre-inits cbuf/sbox/alive/rankbuf/cnt.
// ---------------------------------------------------------------------------
__global__ __launch_bounds__(256) void decode_kernel(
    const float* __restrict__ out0, const float* __restrict__ fgbuf,
    float4* __restrict__ roibuf, u64* __restrict__ keys,
    float* __restrict__ anchor_out, float* __restrict__ out,
    u32* __restrict__ hist, u64* __restrict__ cbuf,
    float4* __restrict__ sbox, u64* __restrict__ alive,
    u32* __restrict__ rankbuf, u32* __restrict__ cnt,
    const int* __restrict__ imgh_p, const int* __restrict__ imgw_p) {
  int gid = blockIdx.x * 256 + threadIdx.x;   // < 131072
  if (gid < 16384) { cbuf[gid] = ~0ull; rankbuf[gid] = 0u; }
  if (gid < 12288) sbox[gid] = make_float4(0.f, 0.f, 0.f, 0.f);
  if (gid < 192) alive[gid] = 0ull;
  if (gid < 4) cnt[gid] = 0u;
  if (gid < 3600) {
    if (gid < 2400) out[O2 + gid] = 0.f;
    else if (gid < 3000) out[O3 + (gid - 2400)] = (float)((gid - 2400) / 300);
    else out[O5 + (gid - 3000)] = 0.f;
  }
  int n = gid >> 16, k = gid & (SEG - 1);
  if (k >= NANCH) return;
  int a = k % 9;
  int p = k / 9;
  int py = p >> 6, px = p & 63;

  const double R[3] = {0.5, 1.0, 2.0};
  const double S[3] = {8.0, 16.0, 32.0};
  double r = R[a / 3], s = S[a - (a / 3) * 3];
  double hd = 16.0 * s * sqrt(r);
  double wd = 16.0 * s * sqrt(1.0 / r);
  float ay1 = (float)(8.0 - hd / 2.0) + (float)(py * 16);
  float ax1 = (float)(8.0 - wd / 2.0) + (float)(px * 16);
  float ay2 = (float)(8.0 + hd / 2.0) + (float)(py * 16);
  float ax2 = (float)(8.0 + wd / 2.0) + (float)(px * 16);
  if (n == 0) {
    *(float4*)(anchor_out + ((size_t)k << 2)) = make_float4(ay1, ax1, ay2, ax2);
  }
  float ahk = ay2 - ay1, awk = ax2 - ax1;
  float acy = ay1 + 0.5f * ahk, acx = ax1 + 0.5f * awk;
  float4 lv = *(const float4*)(out0 + ((size_t)(n * NANCH + k) << 2));
  float dy = lv.x, dx = lv.y, dh = lv.z, dw = lv.w;
  float cy = dy * ahk + acy;
  float cx = dx * awk + acx;
  float bh = expf(dh) * ahk;
  float bw = expf(dw) * awk;
  float img_h = (float)imgh_p[0], img_w = (float)imgw_p[0];
  float y1 = fminf(fmaxf(cy - 0.5f * bh, 0.f), img_h);
  float x1 = fminf(fmaxf(cx - 0.5f * bw, 0.f), img_w);
  float y2 = fminf(fmaxf(cy + 0.5f * bh, 0.f), img_h);
  float x2 = fminf(fmaxf(cx + 0.5f * bw, 0.f), img_w);
  bool valid = ((y2 - y1) >= 16.f) && ((x2 - x1) >= 16.f);
  float sc = valid ? fgbuf[n * NANCH + k] : -INFINITY;
  roibuf[n * NANCH + k] = make_float4(y1, x1, y2, x2);
  unsigned int b = __float_as_uint(sc);
  unsigned int m = b ^ ((b & 0x80000000u) ? 0xFFFFFFFFu : 0x80000000u);
  u32 hk = ~m;
  keys[gid] = ((u64)hk << 32) | (unsigned int)k;
  if (hk < 0xFF800000u) atomicAdd(&hist[(n << 16) + (hk >> 16)], 1u);
}

// ---------------------------------------------------------------------------
// 4a. R14 fused threshold+compact: grid (18,2). Every block REDUNDANTLY
// computes the rank-6000 bin T from the 65536-bin histogram (integer-only,
// deterministic -> identical T across blocks, same value as the old
// thresh_kernel): 256 bins/thread folded into 16 register group-sums,
// 8-round block scan, winner refines group -> bin. Then compacts its
// 2048-key slice with wave-aggregated global atomicAdd slot allocation.
// Removes the separate 2-block thresh launch. cbuf order is arbitrary but
// rank_scatter orders by rank — identical final outputs.
// ---------------------------------------------------------------------------
__global__ __launch_bounds__(256) void compact_kernel(
    const u32* __restrict__ hist, const u64* __restrict__ keys,
    u64* __restrict__ cbuf, u32* __restrict__ cnt) {
  __shared__ u32 sp[264];
  __shared__ u32 sT;
  const int n = blockIdx.y, t = threadIdx.x;

  // ---- redundant threshold scan: thread t covers bins [t*256,(t+1)*256)
  const uint4* hp = (const uint4*)(hist + (n << 16));
  u32 grp[16];                  // 16 group-sums of 16 consecutive bins each
  u32 s = 0;
#pragma unroll
  for (int g = 0; g < 16; ++g) {
    u32 gs = 0;
#pragma unroll
    for (int q = 0; q < 4; ++q) {
      uint4 v = hp[t * 64 + g * 4 + q];
      gs += v.x + v.y + v.z + v.w;
    }
    grp[g] = gs;
    s += gs;
  }
  if (t == 0) sT = 0u;          // total==0 -> T=0; no valid key passes anyway
  sp[SCX(t)] = s;
  __syncthreads();
  for (int off = 1; off < 256; off <<= 1) {
    u32 v = (t >= off) ? sp[SCX(t - off)] : 0u;
    __syncthreads();
    sp[SCX(t)] += v;
    __syncthreads();
  }
  u32 total = sp[SCX(255)];
  u32 target = total < (u32)N_PRE ? total : (u32)N_PRE;
  u32 mycum = sp[SCX(t)];
  u32 prev = t ? sp[SCX(t - 1)] : 0u;
  if (total > 0 && mycum >= target && prev < target) {
    u32 base = prev;
    int gsel = 0;
    bool found = false;
#pragma unroll
    for (int g = 0; g < 16; ++g) {            // find group (unrolled, reg-idx)
      if (!found) {
        if (base + grp[g] >= target) { gsel = g; found = true; }
        else base += grp[g];
      }
    }
    u32 binv[16];
#pragma unroll
    for (int q = 0; q < 4; ++q) {             // reload winning group's 16 bins
      uint4 v = hp[t * 64 + gsel * 4 + q];
      binv[4 * q + 0] = v.x; binv[4 * q + 1] = v.y;
      binv[4 * q + 2] = v.z; binv[4 * q + 3] = v.w;
    }
    u32 b2 = base, bsel = 0u;
    bool f2 = false;
#pragma unroll
    for (int j = 0; j < 16; ++j) {            // walk to exact bin
      if (!f2) {
        b2 += binv[j];
        if (b2 >= target) { bsel = (u32)((t << 8) + (gsel << 4) + j); f2 = true; }
      }
    }
    sT = bsel;
  }
  __syncthreads();
  const u32 T = sT;

  // ---- compact this block's 2048-key slice
  const int lane = t & 63;
  const u64 below = lane ? (~0ull >> (64 - lane)) : 0ull;
  const int i0 = blockIdx.x * 2048;
  for (int i = i0 + t; i < i0 + 2048; i += 256) {
    u64 key = keys[(n << 16) + i];
    u32 hk = (u32)(key >> 32);
    bool take = hk < 0xFF800000u && (hk >> 16) <= T;
    u64 bal = __ballot(take);
    u32 base = 0;
    if (lane == 0 && bal) base = atomicAdd(&cnt[n], (u32)__popcll(bal));
    base = (u32)__shfl((int)base, 0);
    if (take) {
      u32 slot = base + (u32)__popcll(bal & below);
      if (slot < (u32)CAP) cbuf[(n << 13) + slot] = key;
    }
  }
}

// ---------------------------------------------------------------------------
// 4b. rank-by-counting, J-SPLIT. Partial ranks over 1024-key chunks on
// 512 blocks (2/CU, full GPU), atomicAdd into pre-zeroed rankbuf.
// rank[i] = #{j: key_j < key_i}; keys unique -> rank == sorted position.
// ---------------------------------------------------------------------------
#define JTILE 1024
__global__ __launch_bounds__(256) void rank_partial(
    const u64* __restrict__ cbuf, u32* __restrict__ rankbuf) {
  __shared__ u64 lk[JTILE];
  const int n = blockIdx.z;
  const int i = blockIdx.x * 256 + threadIdx.x;    // 0..8191
  const int j0 = blockIdx.y * JTILE;
  const u64* cb = cbuf + (n << 13);
  const u64 mykey = cb[i];
  for (int e = threadIdx.x; e < JTILE; e += 256) lk[e] = cb[j0 + e];
  __syncthreads();
  u32 r = 0;
#pragma unroll 8
  for (int j = 0; j < JTILE; ++j) r += (lk[j] < mykey) ? 1u : 0u;
  atomicAdd(&rankbuf[(n << 13) + i], r);
}

// ---------------------------------------------------------------------------
// 4c. scatter by rank: sbox[rank] = box, alive bit rank (rank < 6000).
// ---------------------------------------------------------------------------
__global__ __launch_bounds__(256) void rank_scatter(
    const u64* __restrict__ cbuf, const u32* __restrict__ rankbuf,
    const float4* __restrict__ roibuf,
    float4* __restrict__ sbox, u64* __restrict__ alive) {
  const int n = blockIdx.y;
  const int i = blockIdx.x * 256 + threadIdx.x;    // 0..8191
  u64 mykey = cbuf[(n << 13) + i];
  if (mykey == ~0ull) return;
  u32 rank = rankbuf[(n << 13) + i];
  if (rank < (u32)N_PRE) {
    u32 k = (u32)(mykey & 0xFFFFFFFFull);
    sbox[n * NPADC + rank] = roibuf[(size_t)n * NANCH + k];
    atomicOr(&alive[n * NW + (rank >> 6)], 1ull << (rank & 63));
  }
}

// ---------------------------------------------------------------------------
// 6b. build suppression matrix — UPPER-TRIANGLE only (w >= g).
// ---------------------------------------------------------------------------
__global__ __launch_bounds__(256) void build_mask(
    const float4* __restrict__ sbox, u64* __restrict__ M) {
  __shared__ float4 jb[4][64];
  __shared__ float ja[4][64];
  const int tid = threadIdx.x, lane = tid & 63, wv = tid >> 6;
  const int g = blockIdx.x, q = blockIdx.y, n = blockIdx.z;
  const float4* sb = sbox + n * NPADC;
  float4 bi = sb[(g << 6) + lane];
  float ai = (bi.z - bi.x) * (bi.w - bi.y);
  u64* Mrow = M + ((size_t)(n * NPADC + (g << 6) + lane)) * NW;
#pragma unroll
  for (int it = 0; it < 6; ++it) {
    int w = q * 24 + (it << 2) + wv;
    if (w < g) continue;                 // dead lower-triangle word
    float4 bjl = sb[(w << 6) + lane];
    jb[wv][lane] = bjl;
    ja[wv][lane] = (bjl.z - bjl.x) * (bjl.w - bjl.y);
    u64 bits = 0;
#pragma unroll 8
    for (int j = 0; j < 64; ++j) {
      float4 bj = jb[wv][j];
      float aj = ja[wv][j];
      float ih = fmaxf(fminf(bi.z, bj.z) - fmaxf(bi.x, bj.x), 0.f);
      float iw = fmaxf(fminf(bi.w, bj.w) - fmaxf(bi.y, bj.y), 0.f);
      float inter = ih * iw;
      bool bit = inter / (ai + aj - inter + 1e-9f) > 0.7f;
      bits |= ((u64)bit) << j;
    }
    Mrow[w] = bits;
  }
}

// ---------------------------------------------------------------------------
// 6c. parallel greedy reduce. 1024 threads per image. Serial greedy ballot
// on wave 0; kept-row OR accumulation on threads [256,1024) as a 96-word x
// 8-row-slot grid (one parallel load batch per chunk) into an LDS
// accumulator. Identical decisions/order to the serial version.
// ---------------------------------------------------------------------------
__global__ __launch_bounds__(1024) void nms_reduce(
    const u64* __restrict__ M, const u64* __restrict__ alive,
    const float4* __restrict__ sbox, float* __restrict__ out) {
  const int n = blockIdx.x, t = threadIdx.x;
  const int lane = t & 63, wv = t >> 6;
  float* rois = out + O2 + n * (N_POST * 4);
  float* vmask = out + O5 + n * N_POST;
  const u64* A = alive + n * NW;
  const u64* Mb = M + (size_t)n * NPADC * NW;
  const float4* sb = sbox + n * NPADC;

  __shared__ u64 accLds[NW];      // suppressed-mask accumulator
  __shared__ int rowsS[64];       // kept-row list for the OR threads
  __shared__ int cntS;
  __shared__ int doneS;

  if (t < NW) accLds[t] = 0ull;
  if (t == 0) { doneS = 0; cntS = 0; }

  // wave-0 private greedy state
  u64 aw0 = 0, aw1 = 0;
  u64 dnext = 0;
  float4 bnext = make_float4(0.f, 0.f, 0.f, 0.f);
  int nk = 0;
  const u64 below = lane ? (~0ull >> (64 - lane)) : 0ull;
  if (wv == 0) {
    aw0 = A[lane];
    aw1 = (lane < 32) ? A[64 + lane] : 0ull;
    dnext = Mb[(size_t)lane * NW + 0];
    bnext = sb[lane];
  }

  // OR-thread mapping: threads [256,1024) -> 96 words x 8 row-slots
  const int u = t - 256;
  const int word = (u >= 0) ? (u % 96) : 0;
  const int slot = (u >= 0) ? (u / 96) : 0;

  __syncthreads();

  for (int c = 0; c < 94; ++c) {
    if (wv == 0) {
      u64 dcur = dnext;
      float4 bcur = bnext;
      if (c + 1 < 94) {
        dnext = Mb[(size_t)(((c + 1) << 6) + lane) * NW + (c + 1)];
        bnext = sb[((c + 1) << 6) + lane];
      }
      u64 wacc = accLds[c];                        // LDS broadcast
      u64 aw = (c < 64) ? bcast64(aw0, c) : bcast64(aw1, c - 64);
      u64 alive_u = aw & ~wacc;
      u64 kept = 0;
      if (alive_u) {
        u64 dmask = dcur & below;
        u64 rem = alive_u;
        while (rem) {
          int j = __builtin_ctzll(rem);            // uniform across wave
          kept |= 1ull << j;
          u64 col = __ballot((dmask >> j) & 1);
          rem &= ~(col | (1ull << j));
        }
        int npop = __popcll(kept);
        if ((kept >> lane) & 1ull) {
          int oslot = nk + __popcll(kept & below);
          if (oslot < N_POST) {
            rois[oslot * 4 + 0] = bcur.x; rois[oslot * 4 + 1] = bcur.y;
            rois[oslot * 4 + 2] = bcur.z; rois[oslot * 4 + 3] = bcur.w;
            vmask[oslot] = 1.0f;
          }
          rowsS[__popcll(kept & below)] = (c << 6) + lane;
        }
        if (lane == 0) {
          cntS = npop;
          if (nk + npop >= N_POST) doneS = 1;
        }
        nk += npop;
      } else {
        if (lane == 0) cntS = 0;
      }
    }
    __syncthreads();                 // rowsS/cntS/doneS visible; prev OR done
    if (doneS) break;                // matches serial: break skips the OR
    const int cnt = cntS;
    if (cnt > 0 && u >= 0) {
      int b0 = slot << 3;            // this slot's 8 rows of the kept list
      if (b0 < cnt) {
        int i1 = (b0 + 1 < cnt) ? b0 + 1 : cnt - 1;
        int i2 = (b0 + 2 < cnt) ? b0 + 2 : cnt - 1;
        int i3 = (b0 + 3 < cnt) ? b0 + 3 : cnt - 1;
        int i4 = (b0 + 4 < cnt) ? b0 + 4 : cnt - 1;
        int i5 = (b0 + 5 < cnt) ? b0 + 5 : cnt - 1;
        int i6 = (b0 + 6 < cnt) ? b0 + 6 : cnt - 1;
        int i7 = (b0 + 7 < cnt) ? b0 + 7 : cnt - 1;
        const u64* r0 = Mb + (size_t)rowsS[b0] * NW;
        const u64* r1 = Mb + (size_t)rowsS[i1] * NW;
        const u64* r2 = Mb + (size_t)rowsS[i2] * NW;
        const u64* r3 = Mb + (size_t)rowsS[i3] * NW;
        const u64* r4 = Mb + (size_t)rowsS[i4] * NW;
        const u64* r5 = Mb + (size_t)rowsS[i5] * NW;
        const u64* r6 = Mb + (size_t)rowsS[i6] * NW;
        const u64* r7 = Mb + (size_t)rowsS[i7] * NW;
        u64 p = r0[word] | r1[word] | r2[word] | r3[word]
              | r4[word] | r5[word] | r6[word] | r7[word];
        atomicOr(&accLds[word], p);
      }
    }
    __syncthreads();                 // acc updated before next chunk's read
  }
}

// ---------------------------------------------------------------------------
extern "C" void kernel_launch(void* const* d_in, const int* in_sizes, int n_in,
                              void* d_out, int out_size, void* d_ws, size_t ws_size,
                              hipStream_t stream) {
  const float* x        = (const float*)d_in[0];
  const float* conv1_w  = (const float*)d_in[1];
  const float* conv1_b  = (const float*)d_in[2];
  const float* score_w  = (const float*)d_in[3];
  const float* score_b  = (const float*)d_in[4];
  const float* loc_w    = (const float*)d_in[5];
  const float* loc_b    = (const float*)d_in[6];
  const int*   imgh_p   = (const int*)d_in[7];
  const int*   imgw_p   = (const int*)d_in[8];

  float* out = (float*)d_out;
  float* ws  = (float*)d_ws;

  _Float16* xhi = (_Float16*)(ws + WS_XHI);
  _Float16* xlo = (_Float16*)(ws + WS_XLO);
  _Float16* whi = (_Float16*)(ws + WS_WHI);
  _Float16* wlo = (_Float16*)(ws + WS_WLO);
  float* wslt   = ws + WS_WSLT;
  float* wslb   = ws + WS_WSLB;
  float* hbuf   = ws + WS_H;
  float* guard  = ws + WS_GUARD;
  // overlays (xhi region is dead after conv)
  float* fgbuf   = ws + WS_FG;
  float4* roibuf = (float4*)(ws + WS_ROI);
  u64* keys      = (u64*)(ws + WS_KEYS);
  float4* sbox   = (float4*)(ws + WS_SBOX);
  u64* alive     = (u64*)(ws + WS_ALIVE);
  u64* cbuf      = (u64*)(ws + WS_CBUF);
  u32* hist      = (u32*)(ws + WS_HIST);
  u32* rankbuf   = (u32*)(ws + WS_RANK);
  u32* cnt       = (u32*)(ws + WS_CNT);
  u64* maskbuf   = (u64*)(ws + WS_MASK);   // overlays whi/wlo (dead after conv)

  prep_all<<<5506, 256, 0, stream>>>(x, conv1_w, loc_w, score_w, loc_b, score_b,
                                     (float4*)hbuf, (float4*)guard,
                                     xhi, xlo, whi, wlo, wslt, wslb);

  conv_mfma<<<dim3(64, 4, 2), 256, 0, stream>>>(xhi, xlo, whi, wlo, guard, hbuf);

  head_kernel<<<dim3(64, 2, 4), 256, 0, stream>>>(hbuf, conv1_b, wslt, wslb, out,
                                                  fgbuf, (uint4*)hist);
  decode_kernel<<<512, 256, 0, stream>>>(out, fgbuf, roibuf, keys,
                                         out + O4, out, hist, cbuf, sbox, alive,
                                         rankbuf, cnt, imgh_p, imgw_p);

  compact_kernel<<<dim3(18, 2), 256, 0, stream>>>(hist, keys, cbuf, cnt);
  rank_partial<<<dim3(32, 8, 2), 256, 0, stream>>>(cbuf, rankbuf);
  rank_scatter<<<dim3(32, 2), 256, 0, stream>>>(cbuf, rankbuf, roibuf, sbox, alive);

  build_mask<<<dim3(96, 4, 2), 256, 0, stream>>>(sbox, maskbuf);
  nms_reduce<<<2, 1024, 0, stream>>>(maskbuf, alive, sbox, out);
}